// Round 10
// baseline (265.800 us; speedup 1.0000x reference)
//
#include <hip/hip_runtime.h>
#include <hip/hip_bf16.h>

// QDense: out = s * (U X U^H)[:128,:128] / tr + (1-s) * diag(softmax(rand_w))
// B=512, D=256, O=128.
// Round-10 = round-9 minus ~20 registers to fit 2 blocks/CU (unified <=128):
//   - Q prefetch ring 2-slot -> 1-slot (load after trace MFMAs, ~250cy cover)
//   - pointer quads -> two shared int offsets over uniform bases (saddr loads)
//   - trace parity-split: waves 0-3 trace even jt-octets, waves 4-7 odd
//   - __launch_bounds__(512,4) pins allocator at 128 regs
// X: global->reg direct (fragment order), 2-deep named-scalar ring (r9-proven).
// U-half: swizzled LDS 64KB.  Yt: 16KB.  Total 80KB -> 2 blocks/CU.
// Raw s_barrier + lgkmcnt(0) only; vmcnt stays counted across barriers.
// 1024 blocks (b = bx>>1, k'-half kh = bx&1), 512 thr.

typedef __attribute__((ext_vector_type(4))) float f32x4;
typedef __attribute__((ext_vector_type(8))) short bf16x8;

static __device__ __forceinline__ short f2bf(float f) {   // prep kernels only
    unsigned u = __float_as_uint(f);
    u += 0x7fffu + ((u >> 16) & 1u);
    return (short)(u >> 16);
}

static __device__ __forceinline__ unsigned cvtpk2(float lo, float hi) {
    union { __hip_bfloat162 h; unsigned u; } c;
    c.h = __float22bfloat162_rn(float2{lo, hi});
    return c.u;
}

static __device__ __forceinline__ bf16x8 pack8(f32x4 a, f32x4 b) {
    union { unsigned u[4]; bf16x8 v; } r;
    r.u[0] = cvtpk2(a[0], a[1]);
    r.u[1] = cvtpk2(a[2], a[3]);
    r.u[2] = cvtpk2(b[0], b[1]);
    r.u[3] = cvtpk2(b[2], b[3]);
    return r.v;
}

static __device__ __forceinline__ f32x4 mfma16(bf16x8 a, bf16x8 b, f32x4 c) {
    return __builtin_amdgcn_mfma_f32_16x16x32_bf16(a, b, c, 0, 0, 0);
}

// slice S = (jt = S>>3, ks = S&7) offset from per-lane base, in ELEMENTS
// (floats for X, shorts for Q; both have row stride 256 elements)
#define XGOFF(S) ((((S) >> 3) & 3) * 16384 + ((S) & 7) * 32)

// trace ownership: even jt-octets -> waves 0-3, odd -> waves 4-7
#define TRP(P) (((((P) >> 3) & 1) != 0) ? (w >= 4) : (w < 4))

// ---- prep kernels (r3 verbatim) ----
__global__ void qprep_u(const float* __restrict__ wt,
                        short* __restrict__ Ur, short* __restrict__ Ui) {
    int idx = blockIdx.x * 256 + threadIdx.x;
    float2 v = ((const float2*)wt)[idx];
    Ur[idx] = f2bf(v.x);
    Ui[idx] = f2bf(v.y);
}

__global__ void qprep_ps(const float* __restrict__ rw, const float* __restrict__ lm,
                         float* __restrict__ pv, float* __restrict__ sv) {
    int t = threadIdx.x;
    float w0 = rw[t], w1 = rw[t + 64];
    float m = fmaxf(w0, w1);
    #pragma unroll
    for (int o = 32; o > 0; o >>= 1) m = fmaxf(m, __shfl_xor(m, o));
    float e0 = expf(w0 - m), e1 = expf(w1 - m);
    float ss = e0 + e1;
    #pragma unroll
    for (int o = 32; o > 0; o >>= 1) ss += __shfl_xor(ss, o);
    pv[t] = e0 / ss;
    pv[t + 64] = e1 / ss;
    if (t == 0) sv[0] = 1.f / (1.f + expf(-lm[0]));
}

__global__ void qprep_q(const float* __restrict__ wt,
                        short* __restrict__ Qrb, short* __restrict__ Qib) {
    int j = blockIdx.x;
    int k = threadIdx.x;
    float ar = 0.f, ai = 0.f;
    for (int i = 0; i < 128; ++i) {
        float2 uk = ((const float2*)wt)[i * 256 + k];
        float2 uj = ((const float2*)wt)[i * 256 + j];
        ar += uk.x * uj.x + uk.y * uj.y;
        ai += uk.x * uj.y - uk.y * uj.x;
    }
    Qrb[j * 256 + k] = f2bf(ar);
    Qib[j * 256 + k] = f2bf(ai);
}

// ---- pipeline macros (P is a LITERAL) ----
#define ISSUE_X(S, a, b, c, d) do {                                             \
    a = *(const f32x4*)(xr + xoff + XGOFF(S));                                  \
    b = *(const f32x4*)(xr + xoff + XGOFF(S) + 4);                              \
    c = *(const f32x4*)(xi + xoff + XGOFF(S));                                  \
    d = *(const f32x4*)(xi + xoff + XGOFF(S) + 4);                              \
} while (0)

#define PHASE(P, ga, gb, ia, ib) do {                                           \
    bf16x8 axr = pack8(ga, gb);                                                 \
    bf16x8 axi = pack8(ia, ib);                                                 \
    if ((P) + 2 < 32) ISSUE_X((P) + 2, ga, gb, ia, ib);                         \
    __builtin_amdgcn_sched_barrier(0);  /* pin issued loads above MFMAs */      \
    bf16x8 axrn = axr ^ (short)0x8000;                                          \
    {                                                                           \
        const int uo = uoA + ((((P) & 7) * 64) ^ 0) * 0 +                       \
                       (((((P) & 7) * 64) + g16) ^ swA);                        \
        bf16x8 bur = *(const bf16x8*)(smem + uo);                               \
        bf16x8 bui = *(const bf16x8*)(smem + 32768 + uo);                       \
        yR0 = mfma16(axr,  bur, yR0);                                           \
        yR0 = mfma16(axi,  bui, yR0);                                           \
        yI0 = mfma16(axi,  bur, yI0);                                           \
        yI0 = mfma16(axrn, bui, yI0);                                           \
    }                                                                           \
    {                                                                           \
        const int uo = uoB + (((((P) & 7) * 64) + g16) ^ swB);                  \
        bf16x8 bur = *(const bf16x8*)(smem + uo);                               \
        bf16x8 bui = *(const bf16x8*)(smem + 32768 + uo);                       \
        yR1 = mfma16(axr,  bur, yR1);                                           \
        yR1 = mfma16(axi,  bui, yR1);                                           \
        yI1 = mfma16(axi,  bur, yI1);                                           \
        yI1 = mfma16(axrn, bui, yI1);                                           \
    }                                                                           \
    if (TRP(P)) {                                                               \
        bf16x8 axin = axi ^ (short)0x8000;                                      \
        tr4 = mfma16(axr,  qr0, tr4);                                           \
        tr4 = mfma16(axin, qi0, tr4);                                           \
    }                                                                           \
    if (((P) + 1 < 32) && TRP((P) + 1)) {                                       \
        qr0 = *(const bf16x8*)(Qrb + qoff + XGOFF((P) + 1));                    \
        qi0 = *(const bf16x8*)(Qib + qoff + XGOFF((P) + 1));                    \
    }                                                                           \
} while (0)

#define PH_E(P) PHASE(P, gA0, gA1, gA2, gA3)
#define PH_O(P) PHASE(P, gB0, gB1, gB2, gB3)

// ---- stage B for one jt (all-scalar accumulators, index addressing) ----
#define STAGEB_KS(JT, KS2) do {                                                 \
    const int ub = (JT) * 64 + (KS2) * 32 + g8;                                 \
    bf16x8 aur0 = *(const bf16x8*)(Urg + ib0 * 256 + ub);                       \
    bf16x8 aui0 = *(const bf16x8*)(Uig + ib0 * 256 + ub);                       \
    bf16x8 aur1 = *(const bf16x8*)(Urg + ib1 * 256 + ub);                       \
    bf16x8 aui1 = *(const bf16x8*)(Uig + ib1 * 256 + ub);                       \
    bf16x8 auin0 = aui0 ^ (short)0x8000;                                        \
    bf16x8 auin1 = aui1 ^ (short)0x8000;                                        \
    {                                                                           \
        const int off = ybA + (((KS2) * 64 + g16) ^ ysA);                       \
        bf16x8 byr = *(const bf16x8*)(smem + 65536 + off);                      \
        bf16x8 byi = *(const bf16x8*)(smem + 73728 + off);                      \
        sR00 = mfma16(aur0,  byr, sR00); sR00 = mfma16(auin0, byi, sR00);       \
        sI00 = mfma16(aui0,  byr, sI00); sI00 = mfma16(aur0,  byi, sI00);       \
        sR10 = mfma16(aur1,  byr, sR10); sR10 = mfma16(auin1, byi, sR10);       \
        sI10 = mfma16(aui1,  byr, sI10); sI10 = mfma16(aur1,  byi, sI10);       \
    }                                                                           \
    {                                                                           \
        const int off = ybB + (((KS2) * 64 + g16) ^ ysB);                       \
        bf16x8 byr = *(const bf16x8*)(smem + 65536 + off);                      \
        bf16x8 byi = *(const bf16x8*)(smem + 73728 + off);                      \
        sR01 = mfma16(aur0,  byr, sR01); sR01 = mfma16(auin0, byi, sR01);       \
        sI01 = mfma16(aui0,  byr, sI01); sI01 = mfma16(aur0,  byi, sI01);       \
        sR11 = mfma16(aur1,  byr, sR11); sR11 = mfma16(auin1, byi, sR11);       \
        sI11 = mfma16(aui1,  byr, sI11); sI11 = mfma16(aur1,  byi, sI11);       \
    }                                                                           \
} while (0)

// ---- Yt exchange + stage B ----
#define YT_AND_B(JT) do {                                                       \
    __builtin_amdgcn_s_barrier();          /* stageB(prev) reads done */        \
    __builtin_amdgcn_sched_barrier(0);                                          \
    {                                                                           \
        uint2 v;                                                                \
        v.x = cvtpk2(yR0[0], yR0[1]); v.y = cvtpk2(yR0[2], yR0[3]);             \
        *(uint2*)(smem + 65536 + woA) = v;                                      \
        v.x = cvtpk2(yI0[0], yI0[1]); v.y = cvtpk2(yI0[2], yI0[3]);             \
        *(uint2*)(smem + 73728 + woA) = v;                                      \
        v.x = cvtpk2(yR1[0], yR1[1]); v.y = cvtpk2(yR1[2], yR1[3]);             \
        *(uint2*)(smem + 65536 + woB) = v;                                      \
        v.x = cvtpk2(yI1[0], yI1[1]); v.y = cvtpk2(yI1[2], yI1[3]);             \
        *(uint2*)(smem + 73728 + woB) = v;                                      \
    }                                                                           \
    asm volatile("s_waitcnt lgkmcnt(0)" ::: "memory");                          \
    __builtin_amdgcn_sched_barrier(0);                                          \
    __builtin_amdgcn_s_barrier();                                               \
    __builtin_amdgcn_sched_barrier(0);                                          \
    STAGEB_KS(JT, 0);                                                           \
    STAGEB_KS(JT, 1);                                                           \
    yR0 = zero; yR1 = zero; yI0 = zero; yI1 = zero;                             \
} while (0)

// ---- main fused kernel ----
__global__ __launch_bounds__(512, 4) void qfused(
    const float* __restrict__ xr, const float* __restrict__ xi,
    const short* __restrict__ Urg, const short* __restrict__ Uig,
    const short* __restrict__ Qrb, const short* __restrict__ Qib,
    const float* __restrict__ pv, const float* __restrict__ sv,
    float* __restrict__ out)
{
    // LDS: [0,65536) U-half swizzled (R 0, I 32768); [65536,81920) Yt (R/I).
    __shared__ __align__(16) char smem[81920];

    const int bx   = blockIdx.x;
    const int b    = bx >> 1;
    const int kh   = bx & 1;
    const int tid  = threadIdx.x;
    const int lane = tid & 63;
    const int w    = tid >> 6;
    const int c16  = lane & 15;
    const int g4   = lane >> 4;
    const int g8   = g4 * 8;
    const int g16  = g4 * 16;

    // ---- stage U-half into swizzled LDS (r3-proven) ----
    #pragma unroll
    for (int q = 0; q < 4; ++q) {
        int c    = tid + q * 512;
        int row  = c >> 5;
        int slot = c & 31;
        int ss   = slot ^ (row & 7);
        const short* sr = Urg + (size_t)(kh * 64 + row) * 256 + ss * 8;
        const short* si = Uig + (size_t)(kh * 64 + row) * 256 + ss * 8;
        *(bf16x8*)(smem + row * 512 + slot * 16)         = *(const bf16x8*)sr;
        *(bf16x8*)(smem + 32768 + row * 512 + slot * 16) = *(const bf16x8*)si;
    }

    const int  ja   = (w & 3) * 16;      // stage-A j-group
    const int  kb   = (w >> 2) * 32;     // stage-A k'-group
    const int  wm   = w >> 1;            // stage-B i-quarter
    const int  wn   = w & 1;             // stage-B k'-half-of-half

    // shared int offsets over uniform bases (saddr-form loads)
    const int xoff = (b << 16) + (ja + c16) * 256 + g8;
    const int qoff = (ja + c16) * 256 + g8;

    // precomputed LDS offset parts
    const int klA = kb + c16,      klB = kb + 16 + c16;
    const int uoA = klA * 512,     uoB = klB * 512;       // U row bases
    const int swA = (klA & 7) << 4, swB = (klB & 7) << 4; // swizzle keys
    const int ybA = (wn * 32 + c16) * 128;                // stage-B Yt rows
    const int ybB = (wn * 32 + 16 + c16) * 128;
    const int ysA = ((wn * 32 + c16) & 7) << 4;
    const int ysB = ((wn * 32 + 16 + c16) & 7) << 4;
    const int woA = klA * 128 + ((ja * 2 + g8) ^ swA);    // Yt write offs
    const int woB = klB * 128 + ((ja * 2 + g8) ^ swB);
    const int ib0 = wm * 32 + c16, ib1 = wm * 32 + 16 + c16;

    f32x4 zero = {0.f, 0.f, 0.f, 0.f};
    f32x4 sR00 = zero, sR01 = zero, sR10 = zero, sR11 = zero;
    f32x4 sI00 = zero, sI01 = zero, sI10 = zero, sI11 = zero;
    f32x4 tr4 = zero;
    f32x4 yR0 = zero, yR1 = zero, yI0 = zero, yI1 = zero;

    f32x4 gA0, gA1, gA2, gA3;            // X ring slot A (even slices)
    f32x4 gB0, gB1, gB2, gB3;            // X ring slot B (odd slices)
    bf16x8 qr0 = {}, qi0 = {};           // single-slot Q

    // ---- prologue: issue slices 0,1 + Q slice 0 (lo waves); barrier ----
    ISSUE_X(0, gA0, gA1, gA2, gA3);
    ISSUE_X(1, gB0, gB1, gB2, gB3);
    if (TRP(0)) {
        qr0 = *(const bf16x8*)(Qrb + qoff + XGOFF(0));
        qi0 = *(const bf16x8*)(Qib + qoff + XGOFF(0));
    }
    asm volatile("s_waitcnt lgkmcnt(0)" ::: "memory");   // U ds_writes done
    __builtin_amdgcn_sched_barrier(0);
    __builtin_amdgcn_s_barrier();                        // vmcnt stays counted
    __builtin_amdgcn_sched_barrier(0);

    PH_E(0);  PH_O(1);  PH_E(2);  PH_O(3);  PH_E(4);  PH_O(5);  PH_E(6);  PH_O(7);
    YT_AND_B(0);
    PH_E(8);  PH_O(9);  PH_E(10); PH_O(11); PH_E(12); PH_O(13); PH_E(14); PH_O(15);
    YT_AND_B(1);
    PH_E(16); PH_O(17); PH_E(18); PH_O(19); PH_E(20); PH_O(21); PH_E(22); PH_O(23);
    YT_AND_B(2);
    PH_E(24); PH_O(25); PH_E(26); PH_O(27); PH_E(28); PH_O(29); PH_E(30); PH_O(31);
    YT_AND_B(3);

    // ---- trace: extract diag of tr4 (all waves contributed), reduce ----
    float loc = ((c16 >> 2) == g4) ? tr4[c16 & 3] : 0.f;
    #pragma unroll
    for (int o = 32; o > 0; o >>= 1) loc += __shfl_xor(loc, o);
    __syncthreads();                      // Yt dead; reuse for reduction
    float* red = (float*)(smem + 65536);
    if (lane == 0) red[w] = loc;
    __syncthreads();
    float tr = red[0] + red[1] + red[2] + red[3] + red[4] + red[5] + red[6] + red[7];

    float s     = sv[0];
    float inv   = s / tr;
    float onems = 1.f - s;
    float* outr = out + (size_t)b * 16384;
    float* outi = out + 8388608 + (size_t)b * 16384;

    #define EPI(SRV, SIV, MT, NT) do {                                          \
        int colc = kh * 64 + wn * 32 + (NT) * 16 + c16;                         \
        _Pragma("unroll")                                                       \
        for (int r = 0; r < 4; ++r) {                                           \
            int row = wm * 32 + (MT) * 16 + g4 * 4 + r;                         \
            float vr = SRV[r] * inv;                                            \
            if (row == colc) vr += onems * pv[row];                             \
            outr[row * 128 + colc] = vr;                                        \
            outi[row * 128 + colc] = SIV[r] * inv;                              \
        }                                                                       \
    } while (0)

    EPI(sR00, sI00, 0, 0);
    EPI(sR01, sI01, 0, 1);
    EPI(sR10, sI10, 1, 0);
    EPI(sR11, sI11, 1, 1);
    #undef EPI
}

extern "C" void kernel_launch(void* const* d_in, const int* in_sizes, int n_in,
                              void* d_out, int out_size, void* d_ws, size_t ws_size,
                              hipStream_t stream) {
    (void)in_sizes; (void)n_in; (void)out_size; (void)ws_size;
    const float* xr = (const float*)d_in[0];
    const float* xi = (const float*)d_in[1];
    const float* wt = (const float*)d_in[2];
    const float* rw = (const float*)d_in[3];
    const float* lm = (const float*)d_in[4];

    short* Ur  = (short*)d_ws;                        // 128x256 bf16 (64 KB)
    short* Ui  = Ur + 32768;                          // 64 KB
    float* pv  = (float*)((char*)d_ws + 131072);      // 128 f32
    float* sv  = pv + 128;                            // 1 f32
    short* Qrb = (short*)((char*)d_ws + 135168);      // 256x256 bf16 (128 KB)
    short* Qib = (short*)((char*)d_ws + 266240);      // 128 KB
    float* o   = (float*)d_out;

    qprep_u<<<dim3(128), dim3(256), 0, stream>>>(wt, Ur, Ui);
    qprep_ps<<<dim3(1), dim3(64), 0, stream>>>(rw, lm, pv, sv);
    qprep_q<<<dim3(256), dim3(256), 0, stream>>>(wt, Qrb, Qib);
    qfused<<<dim3(1024), dim3(512), 0, stream>>>(xr, xi, Ur, Ui, Qrb, Qib, pv, sv, o);
}